// Round 2
// baseline (130.153 us; speedup 1.0000x reference)
//
#include <hip/hip_runtime.h>
#include <math.h>

// AlphaBetaFilter: per-(b,c) linear recurrence over T steps.
//   pred = L + sl;  g = a*(x - pred);  L' = pred + g;  sl' = sl + b*g
//   s_t = M s_{t-1} + v x_t,  M = [[1-a,1-a],[-ab,1-ab]];  s_0 = (x_0, 0).
// Three-kernel chunked scan (R7; resubmitted R8 — R7 bench was an infra
// failure, "container failed twice", no kernel verdict):
//   p1 : per-chunk zero-state run -> aggregate w_k (chunk0 = exact state)
//   p1b: ONE prefix scan per row (32 waves total) -> per-chunk init states w2.
//        Replaces p2's redundant per-block O(k) serial w-scan (O(K^2/2) matrix
//        work/row, ~64 MiB redundant LLC reads, 62-round dependent prologue
//        latency on heavy blocks, load imbalance). Bitwise-identical FMA
//        ordering to the old in-p2 scan -> absmax unchanged.
//   p2 : load init state (1 float4), replay chunk (x re-read is LLC-warm),
//        emit outputs. All chunks uniform; reverse dispatch dropped.
// R6 carried: branch-free loops (STEP(x0) from (x0,0) is a no-op), 16-deep
// explicit load batching for ILP, nontemporal stores for out / nt loads for
// p2's single-use x re-read.
// Context (R5/R4): in-kernel global sync (coop grid.sync 228us, spin lookback
// 480us) is stall-bound on 8-XCD MI355X; separate launches win.

#define B_ 32
#define T_ 4096
#define C_ 128
#define K_ 64
#define S_ (T_ / K_)      // 64
#define C2 (C_ / 2)       // 64 float2 lanes per row
#define NCHUNK (B_ * K_)  // 2048
#define BATCH 16

typedef float v2f __attribute__((ext_vector_type(2)));

__device__ __forceinline__ float sig_clamp(float z) {
    float s = 1.0f / (1.0f + expf(-z));
    return fminf(fmaxf(s, 1.0e-4f), 1.0f - 1.0e-4f);
}

#define STEP(xv0, xv1)                                   \
    {                                                    \
        const float p0 = L0 + sl0;                       \
        const float p1 = L1 + sl1;                       \
        const float g0 = a0 * ((xv0) - p0);              \
        const float g1 = a1 * ((xv1) - p1);              \
        L0 = p0 + g0;  sl0 = fmaf(b0, g0, sl0);          \
        L1 = p1 + g1;  sl1 = fmaf(b1, g1, sl1);          \
    }

// Kernel 1: per-chunk aggregates. 4 waves/block, 1 chunk/wave.
__global__ __launch_bounds__(256, 2) void p1_offsets(
        const float* __restrict__ x,
        const float* __restrict__ logit_alpha,
        const float* __restrict__ logit_beta,
        float4* __restrict__ w) {
    const int tid = threadIdx.x & 63;
    const int chunk = blockIdx.x * 4 + (threadIdx.x >> 6);
    const int b = chunk >> 6;
    const int k = chunk & (K_ - 1);

    const float2 la2 = ((const float2*)logit_alpha)[tid];
    const float2 lb2 = ((const float2*)logit_beta)[tid];
    const float a0 = sig_clamp(la2.x), a1 = sig_clamp(la2.y);
    const float b0 = sig_clamp(lb2.x), b1 = sig_clamp(lb2.y);

    const float2* xp = (const float2*)x + ((size_t)b * T_ + (size_t)k * S_) * C2 + tid;

    float2 buf[BATCH];
    float L0, sl0 = 0.0f, L1, sl1 = 0.0f;

    // batch 0 (includes the k==0 init; STEP(x0) from (x0,0) is a no-op)
    #pragma unroll
    for (int i = 0; i < BATCH; ++i) buf[i] = xp[(size_t)i * C2];
    if (k == 0) { L0 = buf[0].x; L1 = buf[0].y; }
    else        { L0 = 0.0f;     L1 = 0.0f;     }
    #pragma unroll
    for (int i = 0; i < BATCH; ++i) STEP(buf[i].x, buf[i].y);

    for (int base = BATCH; base < S_; base += BATCH) {
        #pragma unroll
        for (int i = 0; i < BATCH; ++i) buf[i] = xp[(size_t)(base + i) * C2];
        #pragma unroll
        for (int i = 0; i < BATCH; ++i) STEP(buf[i].x, buf[i].y);
    }

    w[(size_t)chunk * 64 + tid] = make_float4(L0, sl0, L1, sl1);
}

// Kernel 1b: shared prefix scan of row aggregates. One wave per batch row b.
// w2[b*K + k] = state entering chunk k (k>=1); k==0 slot left as-is (p2
// overrides the k==0 init from x0). Same FMA expression order as the old
// in-p2 scan -> bitwise-identical init states.
__global__ __launch_bounds__(64) void p1b_prefix(
        const float* __restrict__ logit_alpha,
        const float* __restrict__ logit_beta,
        const float4* __restrict__ w,
        float4* __restrict__ w2) {
    const int tid = threadIdx.x;   // 64 lanes, 2 channels each
    const int b = blockIdx.x;      // 32 rows

    const float2 la2 = ((const float2*)logit_alpha)[tid];
    const float2 lb2 = ((const float2*)logit_beta)[tid];
    const float a0 = sig_clamp(la2.x), a1 = sig_clamp(la2.y);
    const float b0 = sig_clamp(lb2.x), b1 = sig_clamp(lb2.y);

    // M^S via 6 squarings (S = 64 = 2^6), per channel
    float m00_0 = 1.0f - a0, m01_0 = 1.0f - a0;
    float m10_0 = -a0 * b0,  m11_0 = 1.0f - a0 * b0;
    float m00_1 = 1.0f - a1, m01_1 = 1.0f - a1;
    float m10_1 = -a1 * b1,  m11_1 = 1.0f - a1 * b1;
    #pragma unroll
    for (int i = 0; i < 6; ++i) {
        float n00 = m00_0 * m00_0 + m01_0 * m10_0;
        float n01 = m00_0 * m01_0 + m01_0 * m11_0;
        float n10 = m10_0 * m00_0 + m11_0 * m10_0;
        float n11 = m10_0 * m01_0 + m11_0 * m11_0;
        m00_0 = n00; m01_0 = n01; m10_0 = n10; m11_0 = n11;
        n00 = m00_1 * m00_1 + m01_1 * m10_1;
        n01 = m00_1 * m01_1 + m01_1 * m11_1;
        n10 = m10_1 * m00_1 + m11_1 * m10_1;
        n11 = m10_1 * m01_1 + m11_1 * m11_1;
        m00_1 = n00; m01_1 = n01; m10_1 = n10; m11_1 = n11;
    }

    const float4* wp = w  + ((size_t)b * K_) * 64 + tid;
    float4*       qp = w2 + ((size_t)b * K_) * 64 + tid;

    float4 s = wp[0];
    qp[64] = s;  // state entering chunk 1
    // unroll 8: the 8 wj loads per window are independent of the serial s
    // chain -> compiler hoists them, hiding L2/LLC latency.
    #pragma unroll 8
    for (int k = 2; k < K_; ++k) {
        const float4 wj = wp[(size_t)(k - 1) * 64];
        const float nx = m00_0 * s.x + m01_0 * s.y + wj.x;
        const float ny = m10_0 * s.x + m11_0 * s.y + wj.y;
        const float nz = m00_1 * s.z + m01_1 * s.w + wj.z;
        const float nw = m10_1 * s.z + m11_1 * s.w + wj.w;
        s = make_float4(nx, ny, nz, nw);
        qp[(size_t)k * 64] = s;
    }
}

// Kernel 2: load init state, replay chunk, emit outputs. Uniform chunks.
__global__ __launch_bounds__(256, 2) void p2_emit(
        const float* __restrict__ x,
        const float* __restrict__ logit_alpha,
        const float* __restrict__ logit_beta,
        const float4* __restrict__ w2,
        float* __restrict__ out) {
    const int tid = threadIdx.x & 63;
    const int chunk = blockIdx.x * 4 + (threadIdx.x >> 6);
    const int b = chunk >> 6;
    const int k = chunk & (K_ - 1);

    const float2 la2 = ((const float2*)logit_alpha)[tid];
    const float2 lb2 = ((const float2*)logit_beta)[tid];
    const float a0 = sig_clamp(la2.x), a1 = sig_clamp(la2.y);
    const float b0 = sig_clamp(lb2.x), b1 = sig_clamp(lb2.y);

    const size_t off = ((size_t)b * T_ + (size_t)k * S_) * C2 + tid;
    const v2f* xp = (const v2f*)x + off;
    v2f* op = (v2f*)out + off;

    // init state from shared prefix (k==0 slot is poison; overridden below
    // before any FP op consumes it)
    const float4 s0 = w2[(size_t)chunk * 64 + tid];
    float L0 = s0.x, sl0 = s0.y, L1 = s0.z, sl1 = s0.w;

    v2f buf[BATCH];

    // batch 0 (k==0 init inside; STEP(x0) from (x0,0) is a no-op and out[0]=x0)
    #pragma unroll
    for (int i = 0; i < BATCH; ++i)
        buf[i] = __builtin_nontemporal_load(&xp[(size_t)i * C2]);
    if (k == 0) { L0 = buf[0].x; L1 = buf[0].y; sl0 = 0.0f; sl1 = 0.0f; }
    #pragma unroll
    for (int i = 0; i < BATCH; ++i) {
        STEP(buf[i].x, buf[i].y);
        v2f o; o.x = L0; o.y = L1;
        __builtin_nontemporal_store(o, &op[(size_t)i * C2]);
    }

    for (int base = BATCH; base < S_; base += BATCH) {
        #pragma unroll
        for (int i = 0; i < BATCH; ++i)
            buf[i] = __builtin_nontemporal_load(&xp[(size_t)(base + i) * C2]);
        #pragma unroll
        for (int i = 0; i < BATCH; ++i) {
            STEP(buf[i].x, buf[i].y);
            v2f o; o.x = L0; o.y = L1;
            __builtin_nontemporal_store(o, &op[(size_t)(base + i) * C2]);
        }
    }
}

// Fallback: fully sequential per-(b,c) thread (used only if ws too small).
__global__ void seq_fallback(
        const float* __restrict__ x,
        const float* __restrict__ logit_alpha,
        const float* __restrict__ logit_beta,
        float* __restrict__ out) {
    const int tid = blockIdx.x * blockDim.x + threadIdx.x;
    if (tid >= B_ * C_) return;
    const int b = tid / C_;
    const int c = tid % C_;
    const float a0 = sig_clamp(logit_alpha[c]);
    const float b0 = sig_clamp(logit_beta[c]);
    const float* xp = x + (size_t)b * T_ * C_ + c;
    float* op = out + (size_t)b * T_ * C_ + c;
    float L0 = xp[0], sl0 = 0.0f;
    op[0] = L0;
    for (int t = 1; t < T_; ++t) {
        const float xv = xp[(size_t)t * C_];
        const float p0 = L0 + sl0;
        const float g0 = a0 * (xv - p0);
        L0 = p0 + g0;
        sl0 = fmaf(b0, g0, sl0);
        op[(size_t)t * C_] = L0;
    }
}

extern "C" void kernel_launch(void* const* d_in, const int* in_sizes, int n_in,
                              void* d_out, int out_size, void* d_ws, size_t ws_size,
                              hipStream_t stream) {
    const float* x  = (const float*)d_in[0];
    const float* la = (const float*)d_in[1];
    const float* lb = (const float*)d_in[2];
    float* out = (float*)d_out;

    const size_t slab = (size_t)NCHUNK * 64 * sizeof(float4);  // 2 MiB
    const size_t need = 2 * slab;                              // w + w2

    if (ws_size >= need) {
        float4* w  = (float4*)d_ws;
        float4* w2 = w + (size_t)NCHUNK * 64;
        p1_offsets<<<NCHUNK / 4, 256, 0, stream>>>(x, la, lb, w);
        p1b_prefix<<<B_, 64, 0, stream>>>(la, lb, w, w2);
        p2_emit<<<NCHUNK / 4, 256, 0, stream>>>(x, la, lb, w2, out);
    } else {
        seq_fallback<<<(B_ * C_ + 255) / 256, 256, 0, stream>>>(x, la, lb, out);
    }
}

// Round 3
// 125.514 us; speedup vs baseline: 1.0370x; 1.0370x over previous
//
#include <hip/hip_runtime.h>
#include <math.h>

// AlphaBetaFilter: per-(b,c) linear recurrence over T steps.
//   pred = L + sl;  g = a*(x - pred);  L' = pred + g;  sl' = sl + b*g
//   s_t = M s_{t-1} + v x_t,  M = [[1-a,1-a],[-ab,1-ab]];  s_0 = (x_0, 0).
// Two-kernel chunked scan (R9 = revert to R6 structure + load hoist).
//   R8 post-mortem: splitting the per-row prefix scan into a separate p1b
//   kernel REGRESSED (130.2 vs 126.9): the in-p2 redundant w-scan was already
//   free (hidden by reverse-dispatch overlap; w is 2 MiB L2-resident), and
//   the third launch added a serial 32-wave bubble. Fewer, fatter launches.
//   R9 micro-fix: p2 issues batch-0 x loads BEFORE the M^S + w-scan prologue
//   so the cold-start VMEM latency hides under the serial FMA chain.
//   p1: per-chunk zero-state run -> aggregate w_k (chunk0 = exact state)
//   p2: per-chunk forward scan of row aggregates with M^S, replay chunk
//       (x re-read is LLC-warm), emit outputs. Reverse dispatch: largest-k
//       chunks (most scan work) first.
// R6 carried: branch-free loops (STEP(x0) from (x0,0) is a no-op), 16-deep
// explicit load batching for ILP, nontemporal stores for out / nt loads for
// p2's single-use x re-read.
// Context (R5/R4): in-kernel global sync (coop grid.sync 228us, spin lookback
// 480us) is stall-bound on 8-XCD MI355X; separate launches win.
// Harness note: the ~42us fillBufferAligned dispatches are the 256 MiB
// workspace re-poison — fixed cost in the timed window, not controllable.

#define B_ 32
#define T_ 4096
#define C_ 128
#define K_ 64
#define S_ (T_ / K_)      // 64
#define C2 (C_ / 2)       // 64 float2 lanes per row
#define NCHUNK (B_ * K_)  // 2048
#define BATCH 16

typedef float v2f __attribute__((ext_vector_type(2)));

__device__ __forceinline__ float sig_clamp(float z) {
    float s = 1.0f / (1.0f + expf(-z));
    return fminf(fmaxf(s, 1.0e-4f), 1.0f - 1.0e-4f);
}

#define STEP(xv0, xv1)                                   \
    {                                                    \
        const float p0 = L0 + sl0;                       \
        const float p1 = L1 + sl1;                       \
        const float g0 = a0 * ((xv0) - p0);              \
        const float g1 = a1 * ((xv1) - p1);              \
        L0 = p0 + g0;  sl0 = fmaf(b0, g0, sl0);          \
        L1 = p1 + g1;  sl1 = fmaf(b1, g1, sl1);          \
    }

// Kernel 1: per-chunk aggregates. 4 waves/block, 1 chunk/wave.
__global__ __launch_bounds__(256, 2) void p1_offsets(
        const float* __restrict__ x,
        const float* __restrict__ logit_alpha,
        const float* __restrict__ logit_beta,
        float4* __restrict__ w) {
    const int tid = threadIdx.x & 63;
    const int chunk = blockIdx.x * 4 + (threadIdx.x >> 6);
    const int b = chunk >> 6;
    const int k = chunk & (K_ - 1);

    const float2 la2 = ((const float2*)logit_alpha)[tid];
    const float2 lb2 = ((const float2*)logit_beta)[tid];
    const float a0 = sig_clamp(la2.x), a1 = sig_clamp(la2.y);
    const float b0 = sig_clamp(lb2.x), b1 = sig_clamp(lb2.y);

    const float2* xp = (const float2*)x + ((size_t)b * T_ + (size_t)k * S_) * C2 + tid;

    float2 buf[BATCH];
    float L0, sl0 = 0.0f, L1, sl1 = 0.0f;

    // batch 0 (includes the k==0 init; STEP(x0) from (x0,0) is a no-op)
    #pragma unroll
    for (int i = 0; i < BATCH; ++i) buf[i] = xp[(size_t)i * C2];
    if (k == 0) { L0 = buf[0].x; L1 = buf[0].y; }
    else        { L0 = 0.0f;     L1 = 0.0f;     }
    #pragma unroll
    for (int i = 0; i < BATCH; ++i) STEP(buf[i].x, buf[i].y);

    for (int base = BATCH; base < S_; base += BATCH) {
        #pragma unroll
        for (int i = 0; i < BATCH; ++i) buf[i] = xp[(size_t)(base + i) * C2];
        #pragma unroll
        for (int i = 0; i < BATCH; ++i) STEP(buf[i].x, buf[i].y);
    }

    w[(size_t)chunk * 64 + tid] = make_float4(L0, sl0, L1, sl1);
}

// Kernel 2: scan row aggregates with M^S, replay chunk, emit outputs.
__global__ __launch_bounds__(256, 2) void p2_emit(
        const float* __restrict__ x,
        const float* __restrict__ logit_alpha,
        const float* __restrict__ logit_beta,
        const float4* __restrict__ w,
        float* __restrict__ out) {
    const int tid = threadIdx.x & 63;
    // reverse order: largest-k chunks (most scan work) dispatch first
    const int chunk = (NCHUNK - 1) - (blockIdx.x * 4 + (threadIdx.x >> 6));
    const int b = chunk >> 6;
    const int k = chunk & (K_ - 1);

    const float2 la2 = ((const float2*)logit_alpha)[tid];
    const float2 lb2 = ((const float2*)logit_beta)[tid];
    const float a0 = sig_clamp(la2.x), a1 = sig_clamp(la2.y);
    const float b0 = sig_clamp(lb2.x), b1 = sig_clamp(lb2.y);

    const size_t off = ((size_t)b * T_ + (size_t)k * S_) * C2 + tid;
    const v2f* xp = (const v2f*)x + off;
    v2f* op = (v2f*)out + off;

    // R9: issue batch-0 x loads BEFORE the serial prologue so the VMEM
    // latency hides under the M^S squaring + w-scan FMA chain.
    v2f buf[BATCH];
    #pragma unroll
    for (int i = 0; i < BATCH; ++i)
        buf[i] = __builtin_nontemporal_load(&xp[(size_t)i * C2]);

    float L0, sl0 = 0.0f, L1, sl1 = 0.0f;

    if (k > 0) {
        // M^S via 6 squarings (S = 64 = 2^6), per channel
        float m00_0 = 1.0f - a0, m01_0 = 1.0f - a0;
        float m10_0 = -a0 * b0,  m11_0 = 1.0f - a0 * b0;
        float m00_1 = 1.0f - a1, m01_1 = 1.0f - a1;
        float m10_1 = -a1 * b1,  m11_1 = 1.0f - a1 * b1;
        #pragma unroll
        for (int i = 0; i < 6; ++i) {
            float n00 = m00_0 * m00_0 + m01_0 * m10_0;
            float n01 = m00_0 * m01_0 + m01_0 * m11_0;
            float n10 = m10_0 * m00_0 + m11_0 * m10_0;
            float n11 = m10_0 * m01_0 + m11_0 * m11_0;
            m00_0 = n00; m01_0 = n01; m10_0 = n10; m11_0 = n11;
            n00 = m00_1 * m00_1 + m01_1 * m10_1;
            n01 = m00_1 * m01_1 + m01_1 * m11_1;
            n10 = m10_1 * m00_1 + m11_1 * m10_1;
            n11 = m10_1 * m01_1 + m11_1 * m11_1;
            m00_1 = n00; m01_1 = n01; m10_1 = n10; m11_1 = n11;
        }
        // forward scan of chunks 0..k-1 of this row (w is L2/LLC-resident)
        const float4* wp = w + (size_t)(chunk - k) * 64 + tid;
        float4 s = wp[0];
        #pragma unroll 8
        for (int j = 1; j < k; ++j) {
            const float4 wj = wp[(size_t)j * 64];
            const float nx = m00_0 * s.x + m01_0 * s.y + wj.x;
            const float ny = m10_0 * s.x + m11_0 * s.y + wj.y;
            const float nz = m00_1 * s.z + m01_1 * s.w + wj.z;
            const float nw = m10_1 * s.z + m11_1 * s.w + wj.w;
            s = make_float4(nx, ny, nz, nw);
        }
        L0 = s.x; sl0 = s.y; L1 = s.z; sl1 = s.w;
    }

    // batch 0 (k==0 init inside; STEP(x0) from (x0,0) is a no-op and out[0]=x0)
    if (k == 0) { L0 = buf[0].x; L1 = buf[0].y; sl0 = 0.0f; sl1 = 0.0f; }
    #pragma unroll
    for (int i = 0; i < BATCH; ++i) {
        STEP(buf[i].x, buf[i].y);
        v2f o; o.x = L0; o.y = L1;
        __builtin_nontemporal_store(o, &op[(size_t)i * C2]);
    }

    for (int base = BATCH; base < S_; base += BATCH) {
        #pragma unroll
        for (int i = 0; i < BATCH; ++i)
            buf[i] = __builtin_nontemporal_load(&xp[(size_t)(base + i) * C2]);
        #pragma unroll
        for (int i = 0; i < BATCH; ++i) {
            STEP(buf[i].x, buf[i].y);
            v2f o; o.x = L0; o.y = L1;
            __builtin_nontemporal_store(o, &op[(size_t)(base + i) * C2]);
        }
    }
}

// Fallback: fully sequential per-(b,c) thread (used only if ws too small).
__global__ void seq_fallback(
        const float* __restrict__ x,
        const float* __restrict__ logit_alpha,
        const float* __restrict__ logit_beta,
        float* __restrict__ out) {
    const int tid = blockIdx.x * blockDim.x + threadIdx.x;
    if (tid >= B_ * C_) return;
    const int b = tid / C_;
    const int c = tid % C_;
    const float a0 = sig_clamp(logit_alpha[c]);
    const float b0 = sig_clamp(logit_beta[c]);
    const float* xp = x + (size_t)b * T_ * C_ + c;
    float* op = out + (size_t)b * T_ * C_ + c;
    float L0 = xp[0], sl0 = 0.0f;
    op[0] = L0;
    for (int t = 1; t < T_; ++t) {
        const float xv = xp[(size_t)t * C_];
        const float p0 = L0 + sl0;
        const float g0 = a0 * (xv - p0);
        L0 = p0 + g0;
        sl0 = fmaf(b0, g0, sl0);
        op[(size_t)t * C_] = L0;
    }
}

extern "C" void kernel_launch(void* const* d_in, const int* in_sizes, int n_in,
                              void* d_out, int out_size, void* d_ws, size_t ws_size,
                              hipStream_t stream) {
    const float* x  = (const float*)d_in[0];
    const float* la = (const float*)d_in[1];
    const float* lb = (const float*)d_in[2];
    float* out = (float*)d_out;

    const size_t need = (size_t)NCHUNK * 64 * sizeof(float4);  // w = 2 MiB

    if (ws_size >= need) {
        float4* w = (float4*)d_ws;
        p1_offsets<<<NCHUNK / 4, 256, 0, stream>>>(x, la, lb, w);
        p2_emit<<<NCHUNK / 4, 256, 0, stream>>>(x, la, lb, w, out);
    } else {
        seq_fallback<<<(B_ * C_ + 255) / 256, 256, 0, stream>>>(x, la, lb, out);
    }
}